// Round 1
// baseline (2105.079 us; speedup 1.0000x reference)
//
#include <hip/hip_runtime.h>
#include <hip/hip_bf16.h>

#define NUM_TOK 8192
#define HID 1024
#define INT_DIM 4096
#define NEXP 8
#define NSLOT 16384  /* NUM_TOK * TOP_K */

typedef __bf16 bf16x8 __attribute__((ext_vector_type(8)));
typedef float f32x4 __attribute__((ext_vector_type(4)));

typedef const __attribute__((address_space(1))) unsigned int* gas_t;
typedef __attribute__((address_space(3))) unsigned int* las_t;

__device__ __forceinline__ void gl_lds16(const unsigned short* g, unsigned short* l) {
    __builtin_amdgcn_global_load_lds((gas_t)g, (las_t)l, 16, 0, 0);
}

__device__ __forceinline__ unsigned short f2bf(float f) {
    unsigned int x = __builtin_bit_cast(unsigned int, f);
    x += 0x7fffu + ((x >> 16) & 1u);   // RNE
    return (unsigned short)(x >> 16);
}

// ---------------- fp32 -> bf16 bulk convert (x and weights) ----------------
__global__ void k_cvt(const float* __restrict__ src, unsigned short* __restrict__ dst) {
    size_t i = ((size_t)blockIdx.x * 256 + threadIdx.x) * 8;
    float4 a = *(const float4*)(src + i);
    float4 b = *(const float4*)(src + i + 4);
    union { unsigned short us[8]; uint4 v; } o;
    o.us[0] = f2bf(a.x); o.us[1] = f2bf(a.y); o.us[2] = f2bf(a.z); o.us[3] = f2bf(a.w);
    o.us[4] = f2bf(b.x); o.us[5] = f2bf(b.y); o.us[6] = f2bf(b.z); o.us[7] = f2bf(b.w);
    *(uint4*)(dst + i) = o.v;
}

// ---------------- router ----------------
__global__ __launch_bounds__(256) void k_router(
    const float* __restrict__ x, const float* __restrict__ gw,
    int* __restrict__ g_cnt, float* __restrict__ g_prob, float* __restrict__ g_z,
    int* __restrict__ btok, float* __restrict__ bw)
{
    __shared__ float sGw[NEXP * HID];
    __shared__ float sProb[NEXP];
    __shared__ int   sCnt[NEXP];
    __shared__ float sZ;
    __shared__ int   sBase[NEXP];
    __shared__ int   rE0[64], rP0[64], rE1[64], rP1[64];
    __shared__ float rW0[64], rW1[64];

    int tid = threadIdx.x;
    for (int i = tid; i < NEXP * HID; i += 256) sGw[i] = gw[i];
    if (tid < NEXP) { sProb[tid] = 0.f; sCnt[tid] = 0; }
    if (tid == 0) sZ = 0.f;
    __syncthreads();

    int wave = tid >> 6, lane = tid & 63;
    for (int ti = 0; ti < 16; ++ti) {
        int lt = wave * 16 + ti;
        int t = blockIdx.x * 64 + lt;
        const float* xr = x + (size_t)t * HID;
        float acc[NEXP];
        #pragma unroll
        for (int e = 0; e < NEXP; ++e) acc[e] = 0.f;
        for (int k = lane; k < HID; k += 64) {
            float xv = xr[k];
            #pragma unroll
            for (int e = 0; e < NEXP; ++e) acc[e] += xv * sGw[e * HID + k];
        }
        #pragma unroll
        for (int e = 0; e < NEXP; ++e) {
            #pragma unroll
            for (int off = 32; off > 0; off >>= 1)
                acc[e] += __shfl_xor(acc[e], off);
        }
        if (lane == 0) {
            float m = acc[0];
            #pragma unroll
            for (int e = 1; e < NEXP; ++e) m = fmaxf(m, acc[e]);
            float s = 0.f;
            float p[NEXP];
            #pragma unroll
            for (int e = 0; e < NEXP; ++e) { p[e] = __expf(acc[e] - m); s += p[e]; }
            float inv = 1.f / s;
            float v1 = -1e30f, v2 = -1e30f; int i1 = -1, i2 = -1;
            #pragma unroll
            for (int e = 0; e < NEXP; ++e) {
                float v = acc[e];
                if (v > v1) { v2 = v1; i2 = i1; v1 = v; i1 = e; }
                else if (v > v2) { v2 = v; i2 = e; }
            }
            float e1v = __expf(v1 - m), e2v = __expf(v2 - m);
            float w0 = e1v / (e1v + e2v), w1 = e2v / (e1v + e2v);
            float lse = m + __logf(s);
            #pragma unroll
            for (int e = 0; e < NEXP; ++e) atomicAdd(&sProb[e], p[e] * inv);
            atomicAdd(&sZ, lse * lse);
            int p0 = atomicAdd(&sCnt[i1], 1);
            int p1 = atomicAdd(&sCnt[i2], 1);
            rE0[lt] = i1; rP0[lt] = p0; rE1[lt] = i2; rP1[lt] = p1;
            rW0[lt] = w0; rW1[lt] = w1;
        }
    }
    __syncthreads();
    if (tid < NEXP) {
        sBase[tid] = atomicAdd(&g_cnt[tid], sCnt[tid]);
        atomicAdd(&g_prob[tid], sProb[tid]);
    }
    if (tid == 64) atomicAdd(g_z, sZ);
    __syncthreads();
    if (tid < 64) {
        int t = blockIdx.x * 64 + tid;
        int e0 = rE0[tid], e1 = rE1[tid];
        int gp0 = sBase[e0] + rP0[tid];
        int gp1 = sBase[e1] + rP1[tid];
        btok[e0 * NUM_TOK + gp0] = t;
        btok[e1 * NUM_TOK + gp1] = t;
        bw[e0 * NUM_TOK + gp0] = rW0[tid];
        bw[e1 * NUM_TOK + gp1] = rW1[tid];
    }
}

// ---------------- finalize: offsets + losses ----------------
__global__ void k_finalize(const int* __restrict__ g_cnt, const float* __restrict__ g_prob,
                           const float* __restrict__ g_z, int* __restrict__ offs,
                           float* __restrict__ out_tail)
{
    if (threadIdx.x == 0) {
        int o = 0; float lb = 0.f;
        for (int e = 0; e < NEXP; ++e) {
            offs[e] = o; o += g_cnt[e];
            lb += (float)g_cnt[e] * g_prob[e];
        }
        offs[NEXP] = o;
        out_tail[0] = (float)NEXP * lb / ((float)NUM_TOK * (float)NUM_TOK) * 0.01f;
        out_tail[1] = (g_z[0] / (float)NUM_TOK) * 0.001f;
    }
}

// ==================== deep-pipelined 256x256 GEMM machinery ====================
// 512 thr = 8 waves (2M x 4N). BK=32. LDS: [A0|B0|A1|B1] x 8192 shorts = 64 KB.
// Per K-tile: 2 phases (m-half 0 / m-half 1), 16 MFMA each.
// Swizzle: 16B-chunk c stored at c ^ ((row>>1)&3) (pre-swizzled global source,
// linear gl_lds dest; ds_read applies same XOR) -> 2-lane/bank = conflict-free.
// Pipeline: tile T lives in buf[T&1]. Stages for T+2's {A-m0,B} issue in ph1 of
// group T (those regions' reads of tile T finished at ph0); A-m1 of T+1 issues
// in ph0 of group T (its region's reads finished in ph1 of T-1). Every stage
// targets a region whose previous reads completed a barrier earlier => race-free.
// vmcnt(4) BEFORE the trailing barrier forces each wave's 3-phase-old prefetch
// complete before any wave enters the phase that reads it; never drains to 0.

#define CFENCE asm volatile("" ::: "memory")
#define VMW(n) asm volatile("s_waitcnt vmcnt(" #n ")" ::: "memory")
#define SB0 __builtin_amdgcn_sched_barrier(0)
#define BARR __builtin_amdgcn_s_barrier()

#define MM1(i, n, H) acc[4*(H)+(i)][n] = __builtin_amdgcn_mfma_f32_16x16x32_bf16(af[i], bfr[n], acc[4*(H)+(i)][n], 0, 0, 0)
#define MFMA16(H) do { \
    MM1(0,0,H); MM1(1,0,H); MM1(2,0,H); MM1(3,0,H); \
    MM1(0,1,H); MM1(1,1,H); MM1(2,1,H); MM1(3,1,H); \
    MM1(0,2,H); MM1(1,2,H); MM1(2,2,H); MM1(3,2,H); \
    MM1(0,3,H); MM1(1,3,H); MM1(2,3,H); MM1(3,3,H); \
} while (0)

#define RD_A(BUF, H) do { \
    af[0] = *(const bf16x8*)((BUF) + offA[H][0]); \
    af[1] = *(const bf16x8*)((BUF) + offA[H][1]); \
    af[2] = *(const bf16x8*)((BUF) + offA[H][2]); \
    af[3] = *(const bf16x8*)((BUF) + offA[H][3]); \
} while (0)
#define RD_B(BUF) do { \
    bfr[0] = *(const bf16x8*)((BUF) + offB[0]); \
    bfr[1] = *(const bf16x8*)((BUF) + offB[1]); \
    bfr[2] = *(const bf16x8*)((BUF) + offB[2]); \
    bfr[3] = *(const bf16x8*)((BUF) + offB[3]); \
} while (0)

#define PHASE0(ABUF, BBUF, ...) do { \
    CFENCE; \
    RD_A(ABUF, 0); RD_B(BBUF); \
    __VA_ARGS__; \
    SB0; BARR; \
    __builtin_amdgcn_s_setprio(1); MFMA16(0); __builtin_amdgcn_s_setprio(0); \
    VMW(4); SB0; BARR; \
} while (0)
#define PHASE1(ABUF, ...) do { \
    CFENCE; \
    RD_A(ABUF, 1); \
    __VA_ARGS__; \
    SB0; BARR; \
    __builtin_amdgcn_s_setprio(1); MFMA16(1); __builtin_amdgcn_s_setprio(0); \
    VMW(4); SB0; BARR; \
} while (0)

// ---------------- ffn1: [gate|up] GEMM + SiLU -> h (bf16) ----------------
// Tile: 256 tokens x 128 j-cols (256 B-rows, gate/up interleaved), K=HID.
__global__ __launch_bounds__(512, 2) void k_ffn1(
    const unsigned short* __restrict__ xb, const unsigned short* __restrict__ wgb,
    const unsigned short* __restrict__ wub, unsigned short* __restrict__ h,
    const int* __restrict__ btok, const int* __restrict__ cnt, const int* __restrict__ offs)
{
    int e = blockIdx.x >> 5;
    int mBase = (blockIdx.x & 31) * 256;
    int ne = cnt[e];
    if (mBase >= ne) return;
    int valid = ne - mBase; if (valid > 256) valid = 256;
    int nBase = blockIdx.y * 128;
    int slotBase = offs[e] + mBase;

    __shared__ alignas(16) unsigned short sm[32768];   // 64 KB
    unsigned short* A0 = sm;
    unsigned short* B0 = sm + 8192;
    unsigned short* A1 = sm + 16384;
    unsigned short* B1 = sm + 24576;

    int tid = threadIdx.x;
    int w = tid >> 6, lane = tid & 63;
    int lr4 = lane >> 2, c4 = lane & 3;
    int l16 = lane & 15, quad = lane >> 4;
    int wm = w >> 2, wn = w & 3;

    // A m0 region = rows {0-63,128-191}; m1 = +64. Wave w stages 16 rows/chunk.
    int r0 = (w < 4) ? (w * 16) : (128 + (w - 4) * 16);
    int schunk = c4 ^ ((lr4 >> 1) & 3);

    int ra0 = mBase + r0 + lr4;        if (ra0 > ne - 1) ra0 = ne - 1;
    int ra1 = mBase + r0 + 64 + lr4;   if (ra1 > ne - 1) ra1 = ne - 1;
    const unsigned short* srcA0 = xb + (size_t)btok[e * NUM_TOK + ra0] * HID + schunk * 8;
    const unsigned short* srcA1 = xb + (size_t)btok[e * NUM_TOK + ra1] * HID + schunk * 8;

    // B rows: rb -> j=(rb>>5)*16+(rb&15), is_up=(rb>>4)&1
    int rblo = w * 16 + lr4;
    int rbhi = 128 + rblo;
    int jlo = ((rblo >> 5) << 4) + (rblo & 15);
    int jhi = ((rbhi >> 5) << 4) + (rbhi & 15);
    const unsigned short* wsl = ((rblo >> 4) & 1) ? wub : wgb;
    const unsigned short* wsh = ((rbhi >> 4) & 1) ? wub : wgb;
    const unsigned short* srcBlo = wsl + ((size_t)e * INT_DIM + nBase + jlo) * HID + schunk * 8;
    const unsigned short* srcBhi = wsh + ((size_t)e * INT_DIM + nBase + jhi) * HID + schunk * 8;

    int sA0 = r0 * 32, sA1 = (r0 + 64) * 32;
    int sBlo = (w * 16) * 32, sBhi = (128 + w * 16) * 32;

    unsigned rsw = (unsigned)((quad ^ ((l16 >> 1) & 3)) * 8);
    unsigned offA[2][4], offB[4];
    #pragma unroll
    for (int hh = 0; hh < 2; ++hh)
        #pragma unroll
        for (int i = 0; i < 4; ++i)
            offA[hh][i] = (unsigned)((wm * 128 + hh * 64 + i * 16 + l16) * 32) + rsw;
    #pragma unroll
    for (int n = 0; n < 4; ++n)
        offB[n] = (unsigned)((wn * 64 + n * 16 + l16) * 32) + rsw;

    f32x4 acc[8][4] = {};
    bf16x8 af[4], bfr[4];

    // prologue: tile0 {Am0,Blo,Bhi,Am1} + tile1 {Am0,Blo,Bhi}
    gl_lds16(srcA0, A0 + sA0);
    gl_lds16(srcBlo, B0 + sBlo);
    gl_lds16(srcBhi, B0 + sBhi);
    gl_lds16(srcA1, A0 + sA1);
    gl_lds16(srcA0 + 32, A1 + sA0);
    gl_lds16(srcBlo + 32, B1 + sBlo);
    gl_lds16(srcBhi + 32, B1 + sBhi);
    VMW(4); SB0; BARR;

    #pragma unroll 1
    for (int g = 0; g < 32; g += 2) {
        int k1 = g + 1;
        int k2 = (g + 2 < 32) ? g + 2 : 31;
        int k3 = (g + 3 < 32) ? g + 3 : 31;
        // group g (buf0)
        PHASE0(A0, B0, gl_lds16(srcA1 + k1 * 32, A1 + sA1));
        PHASE1(A0,
               gl_lds16(srcA0 + k2 * 32, A0 + sA0);
               gl_lds16(srcBlo + k2 * 32, B0 + sBlo);
               gl_lds16(srcBhi + k2 * 32, B0 + sBhi));
        // group g+1 (buf1)
        PHASE0(A1, B1, gl_lds16(srcA1 + k2 * 32, A0 + sA1));
        PHASE1(A1,
               gl_lds16(srcA0 + k3 * 32, A1 + sA0);
               gl_lds16(srcBlo + k3 * 32, B1 + sBlo);
               gl_lds16(srcBhi + k3 * 32, B1 + sBhi));
    }

    asm volatile("s_waitcnt vmcnt(0)" ::: "memory");

    // epilogue: ni even = gate, ni odd = up at j = wn*32 + (ni>>1)*16 + l16
    int colBase = nBase + wn * 32;
    #pragma unroll
    for (int mi = 0; mi < 8; ++mi) {
        #pragma unroll
        for (int rr = 0; rr < 4; ++rr) {
            int row = wm * 128 + mi * 16 + quad * 4 + rr;
            if (row < valid) {
                size_t base = (size_t)(slotBase + row) * INT_DIM + colBase;
                #pragma unroll
                for (int p = 0; p < 2; ++p) {
                    float gv = acc[mi][2 * p][rr];
                    float uv = acc[mi][2 * p + 1][rr];
                    float hv = (gv / (1.f + __expf(-gv))) * uv;
                    h[base + p * 16 + l16] = f2bf(hv);
                }
            }
        }
    }
}

// ---------------- ffn2: h @ w_down^T, fused weighted combine via atomicAdd ----------------
// Tile: 256 slots x 256 out-cols; K split x2 across blockIdx.z (atomics merge).
__global__ __launch_bounds__(512, 2) void k_ffn2(
    const unsigned short* __restrict__ h, const unsigned short* __restrict__ wdb,
    float* __restrict__ out,
    const int* __restrict__ btok, const float* __restrict__ bw,
    const int* __restrict__ cnt, const int* __restrict__ offs)
{
    int e = blockIdx.x >> 5;
    int mBase = (blockIdx.x & 31) * 256;
    int ne = cnt[e];
    if (mBase >= ne) return;
    int valid = ne - mBase; if (valid > 256) valid = 256;
    int nBase = blockIdx.y * 256;
    int kOff = blockIdx.z * (INT_DIM / 2);
    int slotBase = offs[e] + mBase;

    __shared__ alignas(16) unsigned short sm[32768];
    unsigned short* A0 = sm;
    unsigned short* B0 = sm + 8192;
    unsigned short* A1 = sm + 16384;
    unsigned short* B1 = sm + 24576;

    int tid = threadIdx.x;
    int w = tid >> 6, lane = tid & 63;
    int lr4 = lane >> 2, c4 = lane & 3;
    int l16 = lane & 15, quad = lane >> 4;
    int wm = w >> 2, wn = w & 3;

    int r0 = (w < 4) ? (w * 16) : (128 + (w - 4) * 16);
    int schunk = c4 ^ ((lr4 >> 1) & 3);

    int ra0 = r0 + lr4;        if (ra0 > valid - 1) ra0 = valid - 1;
    int ra1 = r0 + 64 + lr4;   if (ra1 > valid - 1) ra1 = valid - 1;
    const unsigned short* srcA0 = h + (size_t)(slotBase + ra0) * INT_DIM + kOff + schunk * 8;
    const unsigned short* srcA1 = h + (size_t)(slotBase + ra1) * INT_DIM + kOff + schunk * 8;

    int rblo = w * 16 + lr4;
    int rbhi = 128 + rblo;
    const unsigned short* srcBlo = wdb + ((size_t)e * HID + nBase + rblo) * INT_DIM + kOff + schunk * 8;
    const unsigned short* srcBhi = wdb + ((size_t)e * HID + nBase + rbhi) * INT_DIM + kOff + schunk * 8;

    int sA0 = r0 * 32, sA1 = (r0 + 64) * 32;
    int sBlo = (w * 16) * 32, sBhi = (128 + w * 16) * 32;

    unsigned rsw = (unsigned)((quad ^ ((l16 >> 1) & 3)) * 8);
    unsigned offA[2][4], offB[4];
    #pragma unroll
    for (int hh = 0; hh < 2; ++hh)
        #pragma unroll
        for (int i = 0; i < 4; ++i)
            offA[hh][i] = (unsigned)((wm * 128 + hh * 64 + i * 16 + l16) * 32) + rsw;
    #pragma unroll
    for (int n = 0; n < 4; ++n)
        offB[n] = (unsigned)((wn * 64 + n * 16 + l16) * 32) + rsw;

    f32x4 acc[8][4] = {};
    bf16x8 af[4], bfr[4];

    gl_lds16(srcA0, A0 + sA0);
    gl_lds16(srcBlo, B0 + sBlo);
    gl_lds16(srcBhi, B0 + sBhi);
    gl_lds16(srcA1, A0 + sA1);
    gl_lds16(srcA0 + 32, A1 + sA0);
    gl_lds16(srcBlo + 32, B1 + sBlo);
    gl_lds16(srcBhi + 32, B1 + sBhi);
    VMW(4); SB0; BARR;

    #pragma unroll 1
    for (int g = 0; g < 64; g += 2) {
        int k1 = g + 1;
        int k2 = (g + 2 < 64) ? g + 2 : 63;
        int k3 = (g + 3 < 64) ? g + 3 : 63;
        PHASE0(A0, B0, gl_lds16(srcA1 + k1 * 32, A1 + sA1));
        PHASE1(A0,
               gl_lds16(srcA0 + k2 * 32, A0 + sA0);
               gl_lds16(srcBlo + k2 * 32, B0 + sBlo);
               gl_lds16(srcBhi + k2 * 32, B0 + sBhi));
        PHASE0(A1, B1, gl_lds16(srcA1 + k2 * 32, A0 + sA1));
        PHASE1(A1,
               gl_lds16(srcA0 + k3 * 32, A1 + sA0);
               gl_lds16(srcBlo + k3 * 32, B1 + sBlo);
               gl_lds16(srcBhi + k3 * 32, B1 + sBhi));
    }

    asm volatile("s_waitcnt vmcnt(0)" ::: "memory");

    int colBase = nBase + wn * 64;
    #pragma unroll
    for (int mi = 0; mi < 8; ++mi) {
        #pragma unroll
        for (int rr = 0; rr < 4; ++rr) {
            int row = wm * 128 + mi * 16 + quad * 4 + rr;
            if (row < valid) {
                int slot = mBase + row;
                int tok = btok[e * NUM_TOK + slot];
                float wgt = bw[e * NUM_TOK + slot];
                float* ob = out + (size_t)tok * HID + colBase;
                atomicAdd(ob + 0  + l16, wgt * acc[mi][0][rr]);
                atomicAdd(ob + 16 + l16, wgt * acc[mi][1][rr]);
                atomicAdd(ob + 32 + l16, wgt * acc[mi][2][rr]);
                atomicAdd(ob + 48 + l16, wgt * acc[mi][3][rr]);
            }
        }
    }
}

extern "C" void kernel_launch(void* const* d_in, const int* in_sizes, int n_in,
                              void* d_out, int out_size, void* d_ws, size_t ws_size,
                              hipStream_t stream) {
    const float* x  = (const float*)d_in[0];
    const float* gw = (const float*)d_in[1];
    const float* wg = (const float*)d_in[2];
    const float* wu = (const float*)d_in[3];
    const float* wd = (const float*)d_in[4];
    float* out = (float*)d_out;

    char* p = (char*)d_ws;
    unsigned short* xb  = (unsigned short*)p; p += (size_t)NUM_TOK * HID * 2;        // 16 MB
    unsigned short* h   = (unsigned short*)p; p += (size_t)NSLOT * INT_DIM * 2;      // 128 MB
    unsigned short* wgb = (unsigned short*)p; p += (size_t)NEXP * INT_DIM * HID * 2; // 64 MB
    unsigned short* wub = (unsigned short*)p; p += (size_t)NEXP * INT_DIM * HID * 2; // 64 MB
    unsigned short* wdb = (unsigned short*)p; p += (size_t)NEXP * HID * INT_DIM * 2; // 64 MB
    int* btok           = (int*)p;            p += (size_t)NEXP * NUM_TOK * 4;       // 256 KB
    float* bw           = (float*)p;          p += (size_t)NEXP * NUM_TOK * 4;       // 256 KB
    int* cnt            = (int*)p;            p += 32;
    float* probSum      = (float*)p;          p += 32;
    float* zSum         = (float*)p;          p += 16;
    int* offs           = (int*)p;            p += 64;

    hipMemsetAsync(cnt, 0, 80, stream);
    hipMemsetAsync(out, 0, (size_t)NUM_TOK * HID * sizeof(float), stream);

    k_cvt<<<4096, 256, 0, stream>>>(x, xb);
    k_cvt<<<16384, 256, 0, stream>>>(wg, wgb);
    k_cvt<<<16384, 256, 0, stream>>>(wu, wub);
    k_cvt<<<16384, 256, 0, stream>>>(wd, wdb);
    k_router<<<128, 256, 0, stream>>>(x, gw, cnt, probSum, zSum, btok, bw);
    k_finalize<<<1, 64, 0, stream>>>(cnt, probSum, zSum, offs, out + (size_t)NUM_TOK * HID);
    k_ffn1<<<dim3(256, 32), 512, 0, stream>>>(xb, wgb, wub, h, btok, cnt, offs);
    k_ffn2<<<dim3(256, 4, 2), 512, 0, stream>>>(h, wdb, out, btok, bw, cnt, offs);
}

// Round 2
// 1083.970 us; speedup vs baseline: 1.9420x; 1.9420x over previous
//
#include <hip/hip_runtime.h>
#include <hip/hip_bf16.h>

#define NUM_TOK 8192
#define HID 1024
#define INT_DIM 4096
#define NEXP 8
#define NSLOT 16384  /* NUM_TOK * TOP_K */

typedef __bf16 bf16x8 __attribute__((ext_vector_type(8)));
typedef float f32x4 __attribute__((ext_vector_type(4)));

typedef const __attribute__((address_space(1))) unsigned int* gas_t;
typedef __attribute__((address_space(3))) unsigned int* las_t;

__device__ __forceinline__ void gl_lds16(const unsigned short* g, unsigned short* l) {
    __builtin_amdgcn_global_load_lds((gas_t)g, (las_t)l, 16, 0, 0);
}

__device__ __forceinline__ unsigned short f2bf(float f) {
    unsigned int x = __builtin_bit_cast(unsigned int, f);
    x += 0x7fffu + ((x >> 16) & 1u);   // RNE
    return (unsigned short)(x >> 16);
}

// ---------------- fp32 -> bf16 bulk convert (x and weights) ----------------
__global__ void k_cvt(const float* __restrict__ src, unsigned short* __restrict__ dst) {
    size_t i = ((size_t)blockIdx.x * 256 + threadIdx.x) * 8;
    float4 a = *(const float4*)(src + i);
    float4 b = *(const float4*)(src + i + 4);
    union { unsigned short us[8]; uint4 v; } o;
    o.us[0] = f2bf(a.x); o.us[1] = f2bf(a.y); o.us[2] = f2bf(a.z); o.us[3] = f2bf(a.w);
    o.us[4] = f2bf(b.x); o.us[5] = f2bf(b.y); o.us[6] = f2bf(b.z); o.us[7] = f2bf(b.w);
    *(uint4*)(dst + i) = o.v;
}

// ---------------- router ----------------
__global__ __launch_bounds__(256) void k_router(
    const float* __restrict__ x, const float* __restrict__ gw,
    int* __restrict__ g_cnt, float* __restrict__ g_prob, float* __restrict__ g_z,
    int* __restrict__ btok, float* __restrict__ bw)
{
    __shared__ float sGw[NEXP * HID];
    __shared__ float sProb[NEXP];
    __shared__ int   sCnt[NEXP];
    __shared__ float sZ;
    __shared__ int   sBase[NEXP];
    __shared__ int   rE0[64], rP0[64], rE1[64], rP1[64];
    __shared__ float rW0[64], rW1[64];

    int tid = threadIdx.x;
    for (int i = tid; i < NEXP * HID; i += 256) sGw[i] = gw[i];
    if (tid < NEXP) { sProb[tid] = 0.f; sCnt[tid] = 0; }
    if (tid == 0) sZ = 0.f;
    __syncthreads();

    int wave = tid >> 6, lane = tid & 63;
    for (int ti = 0; ti < 16; ++ti) {
        int lt = wave * 16 + ti;
        int t = blockIdx.x * 64 + lt;
        const float* xr = x + (size_t)t * HID;
        float acc[NEXP];
        #pragma unroll
        for (int e = 0; e < NEXP; ++e) acc[e] = 0.f;
        for (int k = lane; k < HID; k += 64) {
            float xv = xr[k];
            #pragma unroll
            for (int e = 0; e < NEXP; ++e) acc[e] += xv * sGw[e * HID + k];
        }
        #pragma unroll
        for (int e = 0; e < NEXP; ++e) {
            #pragma unroll
            for (int off = 32; off > 0; off >>= 1)
                acc[e] += __shfl_xor(acc[e], off);
        }
        if (lane == 0) {
            float m = acc[0];
            #pragma unroll
            for (int e = 1; e < NEXP; ++e) m = fmaxf(m, acc[e]);
            float s = 0.f;
            float p[NEXP];
            #pragma unroll
            for (int e = 0; e < NEXP; ++e) { p[e] = __expf(acc[e] - m); s += p[e]; }
            float inv = 1.f / s;
            float v1 = -1e30f, v2 = -1e30f; int i1 = -1, i2 = -1;
            #pragma unroll
            for (int e = 0; e < NEXP; ++e) {
                float v = acc[e];
                if (v > v1) { v2 = v1; i2 = i1; v1 = v; i1 = e; }
                else if (v > v2) { v2 = v; i2 = e; }
            }
            float e1v = __expf(v1 - m), e2v = __expf(v2 - m);
            float w0 = e1v / (e1v + e2v), w1 = e2v / (e1v + e2v);
            float lse = m + __logf(s);
            #pragma unroll
            for (int e = 0; e < NEXP; ++e) atomicAdd(&sProb[e], p[e] * inv);
            atomicAdd(&sZ, lse * lse);
            int p0 = atomicAdd(&sCnt[i1], 1);
            int p1 = atomicAdd(&sCnt[i2], 1);
            rE0[lt] = i1; rP0[lt] = p0; rE1[lt] = i2; rP1[lt] = p1;
            rW0[lt] = w0; rW1[lt] = w1;
        }
    }
    __syncthreads();
    if (tid < NEXP) {
        sBase[tid] = atomicAdd(&g_cnt[tid], sCnt[tid]);
        atomicAdd(&g_prob[tid], sProb[tid]);
    }
    if (tid == 64) atomicAdd(g_z, sZ);
    __syncthreads();
    if (tid < 64) {
        int t = blockIdx.x * 64 + tid;
        int e0 = rE0[tid], e1 = rE1[tid];
        int gp0 = sBase[e0] + rP0[tid];
        int gp1 = sBase[e1] + rP1[tid];
        btok[e0 * NUM_TOK + gp0] = t;
        btok[e1 * NUM_TOK + gp1] = t;
        bw[e0 * NUM_TOK + gp0] = rW0[tid];
        bw[e1 * NUM_TOK + gp1] = rW1[tid];
    }
}

// ---------------- finalize: offsets + losses ----------------
__global__ void k_finalize(const int* __restrict__ g_cnt, const float* __restrict__ g_prob,
                           const float* __restrict__ g_z, int* __restrict__ offs,
                           float* __restrict__ out_tail)
{
    if (threadIdx.x == 0) {
        int o = 0; float lb = 0.f;
        for (int e = 0; e < NEXP; ++e) {
            offs[e] = o; o += g_cnt[e];
            lb += (float)g_cnt[e] * g_prob[e];
        }
        offs[NEXP] = o;
        out_tail[0] = (float)NEXP * lb / ((float)NUM_TOK * (float)NUM_TOK) * 0.01f;
        out_tail[1] = (g_z[0] / (float)NUM_TOK) * 0.001f;
    }
}

// ==================== m201-faithful 256x256 / BK=64 / 8-phase GEMM ====================
// 512 thr = 8 waves (2M x 4N). LDS = 2 K-tiles x (A 32KB + B 32KB) = 128 KB.
// Layout (shorts): buf*32768 + {A:0, B:16384} + half*8192; rows of 64 shorts.
// Swizzle: 16B-chunk c stored at c ^ (row&7); global source pre-swizzled
// (gl_lds dest is linear wave-uniform + lane*16), ds_read applies same XOR.
// Per K-tile pair: 8 phases, each {ds_read frag; stage; barrier; MFMA16; barrier};
// counted vmcnt(4) ONLY at phases 4 & 8. Stage slots (WAR: after last read-barrier;
// RAW: forced >=3 phases after issue):
//  ph1: buf1.A(m0+m1) <- T+1 | ph2: buf0.Bn0 <- T+2 | ph3: buf0.Bn1 <- T+2
//  ph4: - [vmcnt4]           | ph5: buf0.A(m0+m1) <- T+2
//  ph6: buf1.Bn0 <- T+3      | ph7: buf1.Bn1 <- T+3 | ph8: - [vmcnt4]

#define CFENCE asm volatile("" ::: "memory")
#define BARRF do { CFENCE; __builtin_amdgcn_s_barrier(); CFENCE; } while (0)
#define VMW(n) asm volatile("s_waitcnt vmcnt(" #n ")" ::: "memory")
#define SP1 __builtin_amdgcn_s_setprio(1)
#define SP0 __builtin_amdgcn_s_setprio(0)

#define STG_A(BUF,H,KT) do { \
    gl_lds16(abase + (srcA[(H)*2+0] + (unsigned)(KT)*64u), sm + (BUF)*32768 + (H)*8192 + w*512); \
    gl_lds16(abase + (srcA[(H)*2+1] + (unsigned)(KT)*64u), sm + (BUF)*32768 + (H)*8192 + 4096 + w*512); \
} while (0)
#define STG_B(BUF,N,KT) do { \
    gl_lds16(bbase + (srcB[(N)*2+0] + (unsigned)(KT)*64u), sm + (BUF)*32768 + 16384 + (N)*8192 + w*512); \
    gl_lds16(bbase + (srcB[(N)*2+1] + (unsigned)(KT)*64u), sm + (BUF)*32768 + 16384 + (N)*8192 + 4096 + w*512); \
} while (0)

#define RD_A4(BUF,H,KK) do { \
    const unsigned short* pa_ = sm + (BUF)*32768 + (unsigned)((wm*128 + (H)*64 + l16) * 64); \
    unsigned sw_ = (KK) ? swz1 : swz0; \
    af4[0] = *(const bf16x8*)(pa_ + sw_); \
    af4[1] = *(const bf16x8*)(pa_ + 1024 + sw_); \
    af4[2] = *(const bf16x8*)(pa_ + 2048 + sw_); \
    af4[3] = *(const bf16x8*)(pa_ + 3072 + sw_); \
} while (0)
#define RD_B4(BUF,N,BR) do { \
    const unsigned short* pb_ = sm + (BUF)*32768 + 16384 + (unsigned)(((N)*128 + wn*32 + l16) * 64); \
    BR[0] = *(const bf16x8*)(pb_ + swz0); \
    BR[1] = *(const bf16x8*)(pb_ + swz1); \
    BR[2] = *(const bf16x8*)(pb_ + 1024 + swz0); \
    BR[3] = *(const bf16x8*)(pb_ + 1024 + swz1); \
} while (0)

#define MF8(H,N,BR,KK) do { \
    acc[(H)*4+0][(N)*2+0] = __builtin_amdgcn_mfma_f32_16x16x32_bf16(af4[0], BR[0+(KK)], acc[(H)*4+0][(N)*2+0], 0,0,0); \
    acc[(H)*4+1][(N)*2+0] = __builtin_amdgcn_mfma_f32_16x16x32_bf16(af4[1], BR[0+(KK)], acc[(H)*4+1][(N)*2+0], 0,0,0); \
    acc[(H)*4+2][(N)*2+0] = __builtin_amdgcn_mfma_f32_16x16x32_bf16(af4[2], BR[0+(KK)], acc[(H)*4+2][(N)*2+0], 0,0,0); \
    acc[(H)*4+3][(N)*2+0] = __builtin_amdgcn_mfma_f32_16x16x32_bf16(af4[3], BR[0+(KK)], acc[(H)*4+3][(N)*2+0], 0,0,0); \
    acc[(H)*4+0][(N)*2+1] = __builtin_amdgcn_mfma_f32_16x16x32_bf16(af4[0], BR[2+(KK)], acc[(H)*4+0][(N)*2+1], 0,0,0); \
    acc[(H)*4+1][(N)*2+1] = __builtin_amdgcn_mfma_f32_16x16x32_bf16(af4[1], BR[2+(KK)], acc[(H)*4+1][(N)*2+1], 0,0,0); \
    acc[(H)*4+2][(N)*2+1] = __builtin_amdgcn_mfma_f32_16x16x32_bf16(af4[2], BR[2+(KK)], acc[(H)*4+2][(N)*2+1], 0,0,0); \
    acc[(H)*4+3][(N)*2+1] = __builtin_amdgcn_mfma_f32_16x16x32_bf16(af4[3], BR[2+(KK)], acc[(H)*4+3][(N)*2+1], 0,0,0); \
} while (0)

#define GEMM_MAIN(NTILES) \
    STG_B(0,0,0); STG_B(0,1,0); STG_A(0,0,0); STG_A(0,1,0); \
    STG_B(1,0,1); STG_B(1,1,1); \
    VMW(4); BARRF; \
    _Pragma("unroll 1") \
    for (int T = 0; T < (NTILES); T += 2) { \
        int k1 = T + 1; \
        int k2 = (T + 2 < (NTILES)) ? T + 2 : (NTILES) - 1; \
        int k3 = (T + 3 < (NTILES)) ? T + 3 : (NTILES) - 1; \
        /* ph1: quad(h0,n0) on buf0 */ \
        RD_A4(0,0,0); RD_B4(0,0,b0); STG_A(1,0,k1); STG_A(1,1,k1); \
        BARRF; SP1; MF8(0,0,b0,0); RD_A4(0,0,1); MF8(0,0,b0,1); SP0; BARRF; \
        /* ph2: quad(h0,n1) */ \
        RD_A4(0,0,0); RD_B4(0,1,b1); STG_B(0,0,k2); \
        BARRF; SP1; MF8(0,1,b1,0); RD_A4(0,0,1); MF8(0,1,b1,1); SP0; BARRF; \
        /* ph3: quad(h1,n1) */ \
        RD_A4(0,1,0); STG_B(0,1,k2); \
        BARRF; SP1; MF8(1,1,b1,0); RD_A4(0,1,1); MF8(1,1,b1,1); SP0; BARRF; \
        /* ph4: quad(h1,n0) + vmcnt */ \
        RD_A4(0,1,0); \
        BARRF; SP1; MF8(1,0,b0,0); RD_A4(0,1,1); MF8(1,0,b0,1); SP0; VMW(4); BARRF; \
        /* ph5: quad(h0,n0) on buf1 */ \
        STG_A(0,0,k2); STG_A(0,1,k2); RD_A4(1,0,0); RD_B4(1,0,b0); \
        BARRF; SP1; MF8(0,0,b0,0); RD_A4(1,0,1); MF8(0,0,b0,1); SP0; BARRF; \
        /* ph6 */ \
        RD_A4(1,0,0); RD_B4(1,1,b1); STG_B(1,0,k3); \
        BARRF; SP1; MF8(0,1,b1,0); RD_A4(1,0,1); MF8(0,1,b1,1); SP0; BARRF; \
        /* ph7 */ \
        RD_A4(1,1,0); STG_B(1,1,k3); \
        BARRF; SP1; MF8(1,1,b1,0); RD_A4(1,1,1); MF8(1,1,b1,1); SP0; BARRF; \
        /* ph8 */ \
        RD_A4(1,1,0); \
        BARRF; SP1; MF8(1,0,b0,0); RD_A4(1,1,1); MF8(1,0,b0,1); SP0; VMW(4); BARRF; \
    } \
    VMW(0);

// ---------------- ffn1: [gate|up] GEMM + SiLU -> h (bf16) ----------------
// Tile: 256 tokens x 128 j-cols (256 B-rows: r -> j=(r>>5)*16+(r&15), up=(r>>4)&1).
__global__ __launch_bounds__(512, 2) void k_ffn1(
    const unsigned short* __restrict__ xb, const unsigned short* __restrict__ wgb,
    const unsigned short* __restrict__ wub, unsigned short* __restrict__ hout,
    const int* __restrict__ btok, const int* __restrict__ cnt, const int* __restrict__ offs)
{
    // XCD-bijective swizzle: 8192 % 8 == 0; contiguous work per XCD shares B panels
    int bswz = (blockIdx.x & 7) * 1024 + (blockIdx.x >> 3);
    int xm = bswz & 255, y = bswz >> 8;
    int e = xm >> 5;
    int mBase = (xm & 31) * 256;
    int ne = cnt[e];
    if (mBase >= ne) return;
    int valid = ne - mBase; if (valid > 256) valid = 256;
    int nBase = y * 128;
    int slotBase = offs[e] + mBase;

    __shared__ alignas(16) unsigned short sm[65536];   // 128 KB

    int tid = threadIdx.x;
    int w = tid >> 6, lane = tid & 63;
    int lr = lane >> 3, q = (lane & 7) ^ lr;
    int l16 = lane & 15, quad = lane >> 4;
    int wm = w >> 2, wn = w & 3;

    unsigned swz0 = (unsigned)((quad ^ (l16 & 7)) * 8);
    unsigned swz1 = (unsigned)(((4 + quad) ^ (l16 & 7)) * 8);

    const unsigned short* abase = xb;
    const unsigned short* bbase = wgb;
    unsigned updelta = (unsigned)(size_t)(wub - wgb);

    unsigned srcA[4], srcB[4];
    #pragma unroll
    for (int hh = 0; hh < 2; ++hh)
        #pragma unroll
        for (int t = 0; t < 2; ++t) {
            int row = mBase + hh * 128 + t * 64 + w * 8 + lr;
            if (row > ne - 1) row = ne - 1;
            srcA[hh*2+t] = (unsigned)btok[e * NUM_TOK + row] * (unsigned)HID + (unsigned)(q * 8);
        }
    #pragma unroll
    for (int n = 0; n < 2; ++n)
        #pragma unroll
        for (int t = 0; t < 2; ++t) {
            int r = n * 128 + t * 64 + w * 8 + lr;
            int j = ((r >> 5) << 4) + (r & 15);
            srcB[n*2+t] = ((unsigned)e * INT_DIM + nBase + j) * (unsigned)HID
                        + (((r >> 4) & 1) ? updelta : 0u) + (unsigned)(q * 8);
        }

    f32x4 acc[8][4] = {};
    bf16x8 af4[4], b0[4], b1[4];

    GEMM_MAIN(16)

    // epilogue: acc[hq][2n]=gate, [2n+1]=up at j = nBase + n*64 + wn*16 + l16
    #pragma unroll
    for (int hq = 0; hq < 8; ++hq) {
        #pragma unroll
        for (int rr = 0; rr < 4; ++rr) {
            int row = wm * 128 + hq * 16 + quad * 4 + rr;
            if (row < valid) {
                size_t base = (size_t)(slotBase + row) * INT_DIM + nBase;
                #pragma unroll
                for (int n = 0; n < 2; ++n) {
                    float gv = acc[hq][2*n][rr];
                    float uv = acc[hq][2*n+1][rr];
                    float hv = (gv / (1.f + __expf(-gv))) * uv;
                    hout[base + n * 64 + wn * 16 + l16] = f2bf(hv);
                }
            }
        }
    }
}

// ---------------- ffn2: h @ w_down^T, fused weighted combine via atomicAdd ----------------
// Tile: 256 slots x 256 out-cols; K split x2 via decoded z (atomics merge).
__global__ __launch_bounds__(512, 2) void k_ffn2(
    const unsigned short* __restrict__ hin, const unsigned short* __restrict__ wdb,
    float* __restrict__ out,
    const int* __restrict__ btok, const float* __restrict__ bw,
    const int* __restrict__ cnt, const int* __restrict__ offs)
{
    int bswz = (blockIdx.x & 7) * 256 + (blockIdx.x >> 3);   // 2048 % 8 == 0
    int xm = bswz & 255, yz = bswz >> 8;
    int y = yz & 3, z = yz >> 2;
    int e = xm >> 5;
    int mBase = (xm & 31) * 256;
    int ne = cnt[e];
    if (mBase >= ne) return;
    int valid = ne - mBase; if (valid > 256) valid = 256;
    int nBase = y * 256;
    int kOff = z * (INT_DIM / 2);
    int slotBase = offs[e] + mBase;

    __shared__ alignas(16) unsigned short sm[65536];

    int tid = threadIdx.x;
    int w = tid >> 6, lane = tid & 63;
    int lr = lane >> 3, q = (lane & 7) ^ lr;
    int l16 = lane & 15, quad = lane >> 4;
    int wm = w >> 2, wn = w & 3;

    unsigned swz0 = (unsigned)((quad ^ (l16 & 7)) * 8);
    unsigned swz1 = (unsigned)(((4 + quad) ^ (l16 & 7)) * 8);

    const unsigned short* abase = hin;
    const unsigned short* bbase = wdb;

    unsigned srcA[4], srcB[4];
    #pragma unroll
    for (int hh = 0; hh < 2; ++hh)
        #pragma unroll
        for (int t = 0; t < 2; ++t) {
            int row = hh * 128 + t * 64 + w * 8 + lr;
            if (row > valid - 1) row = valid - 1;
            srcA[hh*2+t] = (unsigned)(slotBase + row) * (unsigned)INT_DIM
                         + (unsigned)kOff + (unsigned)(q * 8);
        }
    #pragma unroll
    for (int n = 0; n < 2; ++n)
        #pragma unroll
        for (int t = 0; t < 2; ++t) {
            int r = n * 128 + t * 64 + w * 8 + lr;
            srcB[n*2+t] = ((unsigned)e * HID + nBase + r) * (unsigned)INT_DIM
                        + (unsigned)kOff + (unsigned)(q * 8);
        }

    f32x4 acc[8][4] = {};
    bf16x8 af4[4], b0[4], b1[4];

    GEMM_MAIN(32)

    // epilogue: col = nBase + n*128 + wn*32 + nil*16 + l16; acc[hq][2n+nil]
    #pragma unroll
    for (int hq = 0; hq < 8; ++hq) {
        #pragma unroll
        for (int rr = 0; rr < 4; ++rr) {
            int row = wm * 128 + hq * 16 + quad * 4 + rr;
            if (row < valid) {
                int slot = mBase + row;
                int tok = btok[e * NUM_TOK + slot];
                float wgt = bw[e * NUM_TOK + slot];
                float* ob = out + (size_t)tok * HID + nBase;
                atomicAdd(ob + wn * 32 + l16,             wgt * acc[hq][0][rr]);
                atomicAdd(ob + wn * 32 + 16 + l16,        wgt * acc[hq][1][rr]);
                atomicAdd(ob + 128 + wn * 32 + l16,       wgt * acc[hq][2][rr]);
                atomicAdd(ob + 128 + wn * 32 + 16 + l16,  wgt * acc[hq][3][rr]);
            }
        }
    }
}

extern "C" void kernel_launch(void* const* d_in, const int* in_sizes, int n_in,
                              void* d_out, int out_size, void* d_ws, size_t ws_size,
                              hipStream_t stream) {
    const float* x  = (const float*)d_in[0];
    const float* gw = (const float*)d_in[1];
    const float* wg = (const float*)d_in[2];
    const float* wu = (const float*)d_in[3];
    const float* wd = (const float*)d_in[4];
    float* out = (float*)d_out;

    char* p = (char*)d_ws;
    unsigned short* xb  = (unsigned short*)p; p += (size_t)NUM_TOK * HID * 2;        // 16 MB
    unsigned short* h   = (unsigned short*)p; p += (size_t)NSLOT * INT_DIM * 2;      // 128 MB
    unsigned short* wgb = (unsigned short*)p; p += (size_t)NEXP * INT_DIM * HID * 2; // 64 MB
    unsigned short* wub = (unsigned short*)p; p += (size_t)NEXP * INT_DIM * HID * 2; // 64 MB
    unsigned short* wdb = (unsigned short*)p; p += (size_t)NEXP * HID * INT_DIM * 2; // 64 MB
    int* btok           = (int*)p;            p += (size_t)NEXP * NUM_TOK * 4;       // 256 KB
    float* bw           = (float*)p;          p += (size_t)NEXP * NUM_TOK * 4;       // 256 KB
    int* cnt            = (int*)p;            p += 32;
    float* probSum      = (float*)p;          p += 32;
    float* zSum         = (float*)p;          p += 16;
    int* offs           = (int*)p;            p += 64;

    hipMemsetAsync(cnt, 0, 80, stream);
    hipMemsetAsync(out, 0, (size_t)NUM_TOK * HID * sizeof(float), stream);

    k_cvt<<<4096, 256, 0, stream>>>(x, xb);
    k_cvt<<<16384, 256, 0, stream>>>(wg, wgb);
    k_cvt<<<16384, 256, 0, stream>>>(wu, wub);
    k_cvt<<<16384, 256, 0, stream>>>(wd, wdb);
    k_router<<<128, 256, 0, stream>>>(x, gw, cnt, probSum, zSum, btok, bw);
    k_finalize<<<1, 64, 0, stream>>>(cnt, probSum, zSum, offs, out + (size_t)NUM_TOK * HID);
    k_ffn1<<<8192, 512, 0, stream>>>(xb, wgb, wub, h, btok, cnt, offs);
    k_ffn2<<<2048, 512, 0, stream>>>(h, wdb, out, btok, bw, cnt, offs);
}

// Round 3
// 1068.046 us; speedup vs baseline: 1.9710x; 1.0149x over previous
//
#include <hip/hip_runtime.h>
#include <hip/hip_bf16.h>

#define NUM_TOK 8192
#define HID 1024
#define INT_DIM 4096
#define NEXP 8
#define NSLOT 16384  /* NUM_TOK * TOP_K */

typedef __bf16 bf16x8 __attribute__((ext_vector_type(8)));
typedef float f32x4 __attribute__((ext_vector_type(4)));

typedef const __attribute__((address_space(1))) unsigned int* gas_t;
typedef __attribute__((address_space(3))) unsigned int* las_t;

__device__ __forceinline__ void gl_lds16(const unsigned short* g, unsigned short* l) {
    __builtin_amdgcn_global_load_lds((gas_t)g, (las_t)l, 16, 0, 0);
}

__device__ __forceinline__ unsigned short f2bf(float f) {
    unsigned int x = __builtin_bit_cast(unsigned int, f);
    x += 0x7fffu + ((x >> 16) & 1u);   // RNE
    return (unsigned short)(x >> 16);
}

// ---------------- fp32 -> bf16 bulk convert: all 4 tensors in one launch ----------------
__global__ __launch_bounds__(256) void k_cvtall(
    const float* __restrict__ x, const float* __restrict__ wg,
    const float* __restrict__ wu, const float* __restrict__ wd,
    unsigned short* __restrict__ xb, unsigned short* __restrict__ wgb,
    unsigned short* __restrict__ wub, unsigned short* __restrict__ wdb)
{
    int b = blockIdx.x;
    const float* src; unsigned short* dst; size_t base;
    if (b < 4096)       { src = x;  dst = xb;  base = (size_t)b * 2048; }
    else if (b < 20480) { src = wg; dst = wgb; base = (size_t)(b - 4096) * 2048; }
    else if (b < 36864) { src = wu; dst = wub; base = (size_t)(b - 20480) * 2048; }
    else                { src = wd; dst = wdb; base = (size_t)(b - 36864) * 2048; }
    size_t i = base + (size_t)threadIdx.x * 8;
    float4 a = *(const float4*)(src + i);
    float4 c = *(const float4*)(src + i + 4);
    union { unsigned short us[8]; uint4 v; } o;
    o.us[0] = f2bf(a.x); o.us[1] = f2bf(a.y); o.us[2] = f2bf(a.z); o.us[3] = f2bf(a.w);
    o.us[4] = f2bf(c.x); o.us[5] = f2bf(c.y); o.us[6] = f2bf(c.z); o.us[7] = f2bf(c.w);
    *(uint4*)(dst + i) = o.v;
}

// ---------------- router ----------------
__global__ __launch_bounds__(256) void k_router(
    const float* __restrict__ x, const float* __restrict__ gw,
    int* __restrict__ g_cnt, float* __restrict__ g_prob, float* __restrict__ g_z,
    int* __restrict__ btok, float* __restrict__ bw)
{
    __shared__ float sGw[NEXP * HID];
    __shared__ float sProb[NEXP];
    __shared__ int   sCnt[NEXP];
    __shared__ float sZ;
    __shared__ int   sBase[NEXP];
    __shared__ int   rE0[64], rP0[64], rE1[64], rP1[64];
    __shared__ float rW0[64], rW1[64];

    int tid = threadIdx.x;
    for (int i = tid; i < NEXP * HID; i += 256) sGw[i] = gw[i];
    if (tid < NEXP) { sProb[tid] = 0.f; sCnt[tid] = 0; }
    if (tid == 0) sZ = 0.f;
    __syncthreads();

    int wave = tid >> 6, lane = tid & 63;
    for (int ti = 0; ti < 16; ++ti) {
        int lt = wave * 16 + ti;
        int t = blockIdx.x * 64 + lt;
        const float* xr = x + (size_t)t * HID;
        float acc[NEXP];
        #pragma unroll
        for (int e = 0; e < NEXP; ++e) acc[e] = 0.f;
        for (int k = lane; k < HID; k += 64) {
            float xv = xr[k];
            #pragma unroll
            for (int e = 0; e < NEXP; ++e) acc[e] += xv * sGw[e * HID + k];
        }
        #pragma unroll
        for (int e = 0; e < NEXP; ++e) {
            #pragma unroll
            for (int off = 32; off > 0; off >>= 1)
                acc[e] += __shfl_xor(acc[e], off);
        }
        if (lane == 0) {
            float m = acc[0];
            #pragma unroll
            for (int e = 1; e < NEXP; ++e) m = fmaxf(m, acc[e]);
            float s = 0.f;
            float p[NEXP];
            #pragma unroll
            for (int e = 0; e < NEXP; ++e) { p[e] = __expf(acc[e] - m); s += p[e]; }
            float inv = 1.f / s;
            float v1 = -1e30f, v2 = -1e30f; int i1 = -1, i2 = -1;
            #pragma unroll
            for (int e = 0; e < NEXP; ++e) {
                float v = acc[e];
                if (v > v1) { v2 = v1; i2 = i1; v1 = v; i1 = e; }
                else if (v > v2) { v2 = v; i2 = e; }
            }
            float e1v = __expf(v1 - m), e2v = __expf(v2 - m);
            float w0 = e1v / (e1v + e2v), w1 = e2v / (e1v + e2v);
            float lse = m + __logf(s);
            #pragma unroll
            for (int e = 0; e < NEXP; ++e) atomicAdd(&sProb[e], p[e] * inv);
            atomicAdd(&sZ, lse * lse);
            int p0 = atomicAdd(&sCnt[i1], 1);
            int p1 = atomicAdd(&sCnt[i2], 1);
            rE0[lt] = i1; rP0[lt] = p0; rE1[lt] = i2; rP1[lt] = p1;
            rW0[lt] = w0; rW1[lt] = w1;
        }
    }
    __syncthreads();
    if (tid < NEXP) {
        sBase[tid] = atomicAdd(&g_cnt[tid], sCnt[tid]);
        atomicAdd(&g_prob[tid], sProb[tid]);
    }
    if (tid == 64) atomicAdd(g_z, sZ);
    __syncthreads();
    if (tid < 64) {
        int t = blockIdx.x * 64 + tid;
        int e0 = rE0[tid], e1 = rE1[tid];
        int gp0 = sBase[e0] + rP0[tid];
        int gp1 = sBase[e1] + rP1[tid];
        btok[e0 * NUM_TOK + gp0] = t;
        btok[e1 * NUM_TOK + gp1] = t;
        bw[e0 * NUM_TOK + gp0] = rW0[tid];
        bw[e1 * NUM_TOK + gp1] = rW1[tid];
    }
}

// ---------------- finalize: offsets + losses ----------------
__global__ void k_finalize(const int* __restrict__ g_cnt, const float* __restrict__ g_prob,
                           const float* __restrict__ g_z, int* __restrict__ offs,
                           float* __restrict__ out_tail)
{
    if (threadIdx.x == 0) {
        int o = 0; float lb = 0.f;
        for (int e = 0; e < NEXP; ++e) {
            offs[e] = o; o += g_cnt[e];
            lb += (float)g_cnt[e] * g_prob[e];
        }
        offs[NEXP] = o;
        out_tail[0] = (float)NEXP * lb / ((float)NUM_TOK * (float)NUM_TOK) * 0.01f;
        out_tail[1] = (g_z[0] / (float)NUM_TOK) * 0.001f;
    }
}

// ==================== 256x256 / BK=64 / 8-phase GEMM (read-dedup'd) ====================
// 512 thr = 8 waves (2M x 4N). LDS = 2 K-tiles x (A 32KB + B 32KB) = 128 KB.
// Phases are fixed (H,kk) x all-N: ph1 reads A(H0,kk0) 4xb128 + ALL B 8xb128
// (b0,b1 stay in regs through ph4); ph2-4 read only 4 A-frags each.
// => 24 ds_read_b128 per K-tile per wave (data minimum), was 40.
// Stage slots / counted vmcnt(4)@ph4,ph8 unchanged from verified round-2 audit:
//  ph1: buf1.A <- T+1 | ph2: buf0.Bn0 <- T+2 | ph3: buf0.Bn1 <- T+2 | ph4: vmcnt4
//  ph5: buf0.A <- T+2 | ph6: buf1.Bn0 <- T+3 | ph7: buf1.Bn1 <- T+3 | ph8: vmcnt4

#define CFENCE asm volatile("" ::: "memory")
#define BARRF do { CFENCE; __builtin_amdgcn_s_barrier(); CFENCE; } while (0)
#define VMW(n) asm volatile("s_waitcnt vmcnt(" #n ")" ::: "memory")
#define SP1 __builtin_amdgcn_s_setprio(1)
#define SP0 __builtin_amdgcn_s_setprio(0)

#define STG_A(BUF,H,KT) do { \
    gl_lds16(abase + (srcA[(H)*2+0] + (unsigned)(KT)*64u), sm + (BUF)*32768 + (H)*8192 + ldsW); \
    gl_lds16(abase + (srcA[(H)*2+1] + (unsigned)(KT)*64u), sm + (BUF)*32768 + (H)*8192 + 4096 + ldsW); \
} while (0)
#define STG_B(BUF,N,KT) do { \
    gl_lds16(bbase + (srcB[(N)*2+0] + (unsigned)(KT)*64u), sm + (BUF)*32768 + 16384 + (N)*8192 + ldsW); \
    gl_lds16(bbase + (srcB[(N)*2+1] + (unsigned)(KT)*64u), sm + (BUF)*32768 + 16384 + (N)*8192 + 4096 + ldsW); \
} while (0)

// loop-invariant LDS read offsets (shorts): oA{buf}{kk}, oB{buf}{swz-sel}
#define RD_A4(BUF,H,KK) do { \
    unsigned pa_ = (KK) ? oA##BUF##1 : oA##BUF##0; \
    af4[0] = *(const bf16x8*)(sm + pa_ + (H)*4096);        \
    af4[1] = *(const bf16x8*)(sm + pa_ + (H)*4096 + 1024); \
    af4[2] = *(const bf16x8*)(sm + pa_ + (H)*4096 + 2048); \
    af4[3] = *(const bf16x8*)(sm + pa_ + (H)*4096 + 3072); \
} while (0)
#define RD_B4(BUF,N,BR) do { \
    BR[0] = *(const bf16x8*)(sm + oB##BUF##0 + (N)*8192);        \
    BR[1] = *(const bf16x8*)(sm + oB##BUF##1 + (N)*8192);        \
    BR[2] = *(const bf16x8*)(sm + oB##BUF##0 + (N)*8192 + 1024); \
    BR[3] = *(const bf16x8*)(sm + oB##BUF##1 + (N)*8192 + 1024); \
} while (0)

#define MM(I,N,H,BF) acc[(H)*4+(I)][N] = __builtin_amdgcn_mfma_f32_16x16x32_bf16(af4[I], BF, acc[(H)*4+(I)][N], 0, 0, 0)
#define MF16(H,KK) do { \
    MM(0,0,H,b0[KK]);   MM(1,0,H,b0[KK]);   MM(2,0,H,b0[KK]);   MM(3,0,H,b0[KK]);   \
    MM(0,1,H,b0[2+KK]); MM(1,1,H,b0[2+KK]); MM(2,1,H,b0[2+KK]); MM(3,1,H,b0[2+KK]); \
    MM(0,2,H,b1[KK]);   MM(1,2,H,b1[KK]);   MM(2,2,H,b1[KK]);   MM(3,2,H,b1[KK]);   \
    MM(0,3,H,b1[2+KK]); MM(1,3,H,b1[2+KK]); MM(2,3,H,b1[2+KK]); MM(3,3,H,b1[2+KK]); \
} while (0)

#define GEMM_MAIN(NTILES) \
    STG_B(0,0,0); STG_B(0,1,0); STG_A(0,0,0); STG_A(0,1,0); \
    STG_B(1,0,1); STG_B(1,1,1); \
    VMW(4); BARRF; \
    _Pragma("unroll 1") \
    for (int T = 0; T < (NTILES); T += 2) { \
        int k1 = T + 1; \
        int k2 = (T + 2 < (NTILES)) ? T + 2 : (NTILES) - 1; \
        int k3 = (T + 3 < (NTILES)) ? T + 3 : (NTILES) - 1; \
        /* ph1 (buf0): A(H0,kk0) + all B */ \
        RD_A4(0,0,0); RD_B4(0,0,b0); RD_B4(0,1,b1); STG_A(1,0,k1); STG_A(1,1,k1); \
        BARRF; SP1; MF16(0,0); SP0; BARRF; \
        /* ph2 */ \
        RD_A4(0,0,1); STG_B(0,0,k2); \
        BARRF; SP1; MF16(0,1); SP0; BARRF; \
        /* ph3 */ \
        RD_A4(0,1,0); STG_B(0,1,k2); \
        BARRF; SP1; MF16(1,0); SP0; BARRF; \
        /* ph4 */ \
        RD_A4(0,1,1); \
        BARRF; SP1; MF16(1,1); SP0; VMW(4); BARRF; \
        /* ph5 (buf1) */ \
        RD_A4(1,0,0); RD_B4(1,0,b0); RD_B4(1,1,b1); STG_A(0,0,k2); STG_A(0,1,k2); \
        BARRF; SP1; MF16(0,0); SP0; BARRF; \
        /* ph6 */ \
        RD_A4(1,0,1); STG_B(1,0,k3); \
        BARRF; SP1; MF16(0,1); SP0; BARRF; \
        /* ph7 */ \
        RD_A4(1,1,0); STG_B(1,1,k3); \
        BARRF; SP1; MF16(1,0); SP0; BARRF; \
        /* ph8 */ \
        RD_A4(1,1,1); \
        BARRF; SP1; MF16(1,1); SP0; VMW(4); BARRF; \
    } \
    VMW(0);

// ---------------- ffn1: [gate|up] GEMM + SiLU -> h (bf16) ----------------
// Tile: 256 tokens x 128 j-cols (256 B-rows: r -> j=(r>>5)*16+(r&15), up=(r>>4)&1).
__global__ __launch_bounds__(512, 2) void k_ffn1(
    const unsigned short* __restrict__ xb, const unsigned short* __restrict__ wgb,
    const unsigned short* __restrict__ wub, unsigned short* __restrict__ hout,
    const int* __restrict__ btok, const int* __restrict__ cnt, const int* __restrict__ offs)
{
    // XCD-chunked swizzle: chunk = 8 m-tiles x 4 y-panels (32 blocks, one XCD),
    // so concurrent blocks on an XCD share both A-tiles and B-panels in L2.
    int bid = blockIdx.x;
    int xcd = bid & 7, local = bid >> 3;          // local 0..1023
    int c = xcd * 32 + (local >> 5);              // chunk 0..255
    int w5 = local & 31;
    int xm = ((c >> 3) << 3) + (w5 >> 2);         // 0..255
    int y  = ((c & 7) << 2) + (w5 & 3);           // 0..31
    int e = xm >> 5;
    int mBase = (xm & 31) * 256;
    int ne = cnt[e];
    if (mBase >= ne) return;
    int valid = ne - mBase; if (valid > 256) valid = 256;
    int nBase = y * 128;
    int slotBase = offs[e] + mBase;

    __shared__ alignas(16) unsigned short sm[65536];   // 128 KB

    int tid = threadIdx.x;
    int w = tid >> 6, lane = tid & 63;
    int lr = lane >> 3, q = (lane & 7) ^ lr;
    int l16 = lane & 15, quad = lane >> 4;
    int wm = w >> 2, wn = w & 3;
    unsigned ldsW = (unsigned)(w * 512);

    unsigned swz0 = (unsigned)((quad ^ (l16 & 7)) * 8);
    unsigned swz1 = (unsigned)(((4 + quad) ^ (l16 & 7)) * 8);
    unsigned oA00 = (unsigned)((wm * 128 + l16) * 64) + swz0;
    unsigned oA01 = (unsigned)((wm * 128 + l16) * 64) + swz1;
    unsigned oA10 = oA00 + 32768u, oA11 = oA01 + 32768u;
    unsigned oB00 = 16384u + (unsigned)((wn * 32 + l16) * 64) + swz0;
    unsigned oB01 = 16384u + (unsigned)((wn * 32 + l16) * 64) + swz1;
    unsigned oB10 = oB00 + 32768u, oB11 = oB01 + 32768u;

    const unsigned short* abase = xb;
    const unsigned short* bbase = wgb;
    unsigned updelta = (unsigned)(size_t)(wub - wgb);

    unsigned srcA[4], srcB[4];
    #pragma unroll
    for (int hh = 0; hh < 2; ++hh)
        #pragma unroll
        for (int t = 0; t < 2; ++t) {
            int row = mBase + hh * 128 + t * 64 + w * 8 + lr;
            if (row > ne - 1) row = ne - 1;
            srcA[hh*2+t] = (unsigned)btok[e * NUM_TOK + row] * (unsigned)HID + (unsigned)(q * 8);
        }
    #pragma unroll
    for (int n = 0; n < 2; ++n)
        #pragma unroll
        for (int t = 0; t < 2; ++t) {
            int r = n * 128 + t * 64 + w * 8 + lr;
            int j = ((r >> 5) << 4) + (r & 15);
            srcB[n*2+t] = ((unsigned)e * INT_DIM + nBase + j) * (unsigned)HID
                        + (((r >> 4) & 1) ? updelta : 0u) + (unsigned)(q * 8);
        }

    f32x4 acc[8][4] = {};
    bf16x8 af4[4], b0[4], b1[4];

    GEMM_MAIN(16)

    // epilogue: acc[hq][2n]=gate, [2n+1]=up at j = nBase + n*64 + wn*16 + l16
    #pragma unroll
    for (int hq = 0; hq < 8; ++hq) {
        #pragma unroll
        for (int rr = 0; rr < 4; ++rr) {
            int row = wm * 128 + hq * 16 + quad * 4 + rr;
            if (row < valid) {
                size_t base = (size_t)(slotBase + row) * INT_DIM + nBase;
                #pragma unroll
                for (int n = 0; n < 2; ++n) {
                    float gv = acc[hq][2*n][rr];
                    float uv = acc[hq][2*n+1][rr];
                    float hv = (gv / (1.f + __expf(-gv))) * uv;
                    hout[base + n * 64 + wn * 16 + l16] = f2bf(hv);
                }
            }
        }
    }
}

// ---------------- ffn2: h @ w_down^T, fused weighted combine via atomicAdd ----------------
// Tile: 256 slots x 256 out-cols; K split x2 (atomics merge).
__global__ __launch_bounds__(512, 2) void k_ffn2(
    const unsigned short* __restrict__ hin, const unsigned short* __restrict__ wdb,
    float* __restrict__ out,
    const int* __restrict__ btok, const float* __restrict__ bw,
    const int* __restrict__ cnt, const int* __restrict__ offs)
{
    // XCD-chunked: chunk = 4 m-tiles x (4y x 2z) = 32 blocks per XCD.
    int bid = blockIdx.x;
    int xcd = bid & 7, local = bid >> 3;          // 0..255
    int c = xcd * 8 + (local >> 5);               // 0..63
    int w5 = local & 31;
    int xm = c * 4 + (w5 >> 3);                   // 0..255
    int y  = w5 & 3, z = (w5 >> 2) & 1;
    int e = xm >> 5;
    int mBase = (xm & 31) * 256;
    int ne = cnt[e];
    if (mBase >= ne) return;
    int valid = ne - mBase; if (valid > 256) valid = 256;
    int nBase = y * 256;
    int kOff = z * (INT_DIM / 2);
    int slotBase = offs[e] + mBase;

    __shared__ alignas(16) unsigned short sm[65536];

    int tid = threadIdx.x;
    int w = tid >> 6, lane = tid & 63;
    int lr = lane >> 3, q = (lane & 7) ^ lr;
    int l16 = lane & 15, quad = lane >> 4;
    int wm = w >> 2, wn = w & 3;
    unsigned ldsW = (unsigned)(w * 512);

    unsigned swz0 = (unsigned)((quad ^ (l16 & 7)) * 8);
    unsigned swz1 = (unsigned)(((4 + quad) ^ (l16 & 7)) * 8);
    unsigned oA00 = (unsigned)((wm * 128 + l16) * 64) + swz0;
    unsigned oA01 = (unsigned)((wm * 128 + l16) * 64) + swz1;
    unsigned oA10 = oA00 + 32768u, oA11 = oA01 + 32768u;
    unsigned oB00 = 16384u + (unsigned)((wn * 32 + l16) * 64) + swz0;
    unsigned oB01 = 16384u + (unsigned)((wn * 32 + l16) * 64) + swz1;
    unsigned oB10 = oB00 + 32768u, oB11 = oB01 + 32768u;

    const unsigned short* abase = hin;
    const unsigned short* bbase = wdb;

    unsigned srcA[4], srcB[4];
    #pragma unroll
    for (int hh = 0; hh < 2; ++hh)
        #pragma unroll
        for (int t = 0; t < 2; ++t) {
            int row = hh * 128 + t * 64 + w * 8 + lr;
            if (row > valid - 1) row = valid - 1;
            srcA[hh*2+t] = (unsigned)(slotBase + row) * (unsigned)INT_DIM
                         + (unsigned)kOff + (unsigned)(q * 8);
        }
    #pragma unroll
    for (int n = 0; n < 2; ++n)
        #pragma unroll
        for (int t = 0; t < 2; ++t) {
            int r = n * 128 + t * 64 + w * 8 + lr;
            srcB[n*2+t] = ((unsigned)e * HID + nBase + r) * (unsigned)INT_DIM
                        + (unsigned)kOff + (unsigned)(q * 8);
        }

    f32x4 acc[8][4] = {};
    bf16x8 af4[4], b0[4], b1[4];

    GEMM_MAIN(32)

    // epilogue: col = nBase + n*128 + wn*32 + nil*16 + l16; acc[hq][2n+nil]
    #pragma unroll
    for (int hq = 0; hq < 8; ++hq) {
        #pragma unroll
        for (int rr = 0; rr < 4; ++rr) {
            int row = wm * 128 + hq * 16 + quad * 4 + rr;
            if (row < valid) {
                int slot = mBase + row;
                int tok = btok[e * NUM_TOK + slot];
                float wgt = bw[e * NUM_TOK + slot];
                float* ob = out + (size_t)tok * HID + nBase;
                atomicAdd(ob + wn * 32 + l16,             wgt * acc[hq][0][rr]);
                atomicAdd(ob + wn * 32 + 16 + l16,        wgt * acc[hq][1][rr]);
                atomicAdd(ob + 128 + wn * 32 + l16,       wgt * acc[hq][2][rr]);
                atomicAdd(ob + 128 + wn * 32 + 16 + l16,  wgt * acc[hq][3][rr]);
            }
        }
    }
}

extern "C" void kernel_launch(void* const* d_in, const int* in_sizes, int n_in,
                              void* d_out, int out_size, void* d_ws, size_t ws_size,
                              hipStream_t stream) {
    const float* x  = (const float*)d_in[0];
    const float* gw = (const float*)d_in[1];
    const float* wg = (const float*)d_in[2];
    const float* wu = (const float*)d_in[3];
    const float* wd = (const float*)d_in[4];
    float* out = (float*)d_out;

    char* p = (char*)d_ws;
    unsigned short* xb  = (unsigned short*)p; p += (size_t)NUM_TOK * HID * 2;        // 16 MB
    unsigned short* h   = (unsigned short*)p; p += (size_t)NSLOT * INT_DIM * 2;      // 128 MB
    unsigned short* wgb = (unsigned short*)p; p += (size_t)NEXP * INT_DIM * HID * 2; // 64 MB
    unsigned short* wub = (unsigned short*)p; p += (size_t)NEXP * INT_DIM * HID * 2; // 64 MB
    unsigned short* wdb = (unsigned short*)p; p += (size_t)NEXP * HID * INT_DIM * 2; // 64 MB
    int* btok           = (int*)p;            p += (size_t)NEXP * NUM_TOK * 4;       // 256 KB
    float* bw           = (float*)p;          p += (size_t)NEXP * NUM_TOK * 4;       // 256 KB
    int* cnt            = (int*)p;            p += 32;
    float* probSum      = (float*)p;          p += 32;
    float* zSum         = (float*)p;          p += 16;
    int* offs           = (int*)p;            p += 64;

    hipMemsetAsync(cnt, 0, 80, stream);
    hipMemsetAsync(out, 0, (size_t)NUM_TOK * HID * sizeof(float), stream);

    k_cvtall<<<53248, 256, 0, stream>>>(x, wg, wu, wd, xb, wgb, wub, wdb);
    k_router<<<128, 256, 0, stream>>>(x, gw, cnt, probSum, zSum, btok, bw);
    k_finalize<<<1, 64, 0, stream>>>(cnt, probSum, zSum, offs, out + (size_t)NUM_TOK * HID);
    k_ffn1<<<8192, 512, 0, stream>>>(xb, wgb, wub, h, btok, cnt, offs);
    k_ffn2<<<2048, 512, 0, stream>>>(h, wdb, out, btok, bw, cnt, offs);
}